// Round 10
// baseline (1041.740 us; speedup 1.0000x reference)
//
#include <hip/hip_runtime.h>

#define IN_F 4096
#define OUT_F 11008
#define NGROUPS 32
#define M_TOTAL 8192
#define BM 256
#define BN 128
#define BK 32
#define NKT (IN_F / BK)  // 128 K-tiles

typedef _Float16 half_t;
typedef __attribute__((ext_vector_type(8))) _Float16 half8;
typedef __attribute__((ext_vector_type(4))) _Float16 half4v;
typedef __attribute__((ext_vector_type(4))) float f32x4;
typedef __attribute__((ext_vector_type(4))) int i32x4;

typedef __attribute__((address_space(1))) const void gvoid_t;
typedef __attribute__((address_space(3))) void lvoid_t;

// ---------------- prepass 1: x fp32 -> fp16 (RTNE) ----------------
__global__ void convert_x_k(const float* __restrict__ x, half_t* __restrict__ xh) {
  const int n4 = M_TOTAL * IN_F / 4;
  int stride = gridDim.x * blockDim.x;
  for (int i = blockIdx.x * blockDim.x + threadIdx.x; i < n4; i += stride) {
    f32x4 v = __builtin_nontemporal_load((const f32x4*)x + i);
    half4v h;
    h[0] = (_Float16)v[0]; h[1] = (_Float16)v[1];
    h[2] = (_Float16)v[2]; h[3] = (_Float16)v[3];
    ((half4v*)xh)[i] = h;
  }
}

// ---------------- prepass 2: W (int32-materialized int8) * group scale -> fp16 ----------
__global__ void dequant_w_k(const int* __restrict__ wq,
                            const float* __restrict__ scales,
                            half_t* __restrict__ wh) {
  int row = blockIdx.x;
  int t = threadIdx.x;  // 512 threads, 8 weights each
  size_t base = (size_t)row * IN_F + (size_t)t * 8;
  float s = scales[row * NGROUPS + (t >> 4)];
  i32x4 q0 = __builtin_nontemporal_load((const i32x4*)(wq + base));
  i32x4 q1 = __builtin_nontemporal_load((const i32x4*)(wq + base) + 1);
  half8 h;
#pragma unroll
  for (int j = 0; j < 4; ++j) h[j] = (_Float16)((float)q0[j] * s);
#pragma unroll
  for (int j = 0; j < 4; ++j) h[4 + j] = (_Float16)((float)q1[j] * s);
  *(half8*)(wh + base) = h;
}

// ---------------- 256x128 GEMM, 2 blocks/CU, 3-slot LDS rotation ----------------
// Goal: break single-block barrier lockstep. 72 KiB LDS + VGPR<=128 -> 2 blocks/CU
// (16 waves, 4/SIMD); independent barrier groups overlap reads with MFMA.
// LDS slot (24 KiB): A [256 rows][32k] (16 KiB) then B [128 rows][32k] (8 KiB),
// 64 B rows, T2 swizzle c ^= (row&6)<<3 (pre-swizzled source + swizzled read).
// Phase t: rd slot t%3 (8 ds_read_b128/wave); stage tile t+2 -> slot (t+2)%3
// (= slot last read at t-1, freed by its end barrier); BAR; lgkm0; 16 MFMA
// (16x16x32 f16, verified maps); vmcnt(3) retires tile t+1's 3 loads; BAR.

#define BAR() __builtin_amdgcn_s_barrier()
#define SB0() __builtin_amdgcn_sched_barrier(0)
#define PRIO1() __builtin_amdgcn_s_setprio(1)
#define PRIO0() __builtin_amdgcn_s_setprio(0)
#define VMCNT(N) asm volatile("s_waitcnt vmcnt(" #N ")" ::: "memory")
#define LGKM(N) asm volatile("s_waitcnt lgkmcnt(" #N ")" ::: "memory")

// Stage tile KT into slot S: A 2 rounds + B 1 round, 3 global_load_lds/thread.
#define STAGE(KT, S)                                                                   \
  do {                                                                                 \
    char* sb_ = (char*)lds + (S) * 24576;                                              \
    const half_t* gA_ = pAsrc + (KT) * 32;                                             \
    const half_t* gB_ = pBsrc + (KT) * 32;                                             \
    __builtin_amdgcn_global_load_lds((gvoid_t*)gA_, (lvoid_t*)(sb_ + t16), 16, 0, 0);  \
    __builtin_amdgcn_global_load_lds((gvoid_t*)(gA_ + 128 * IN_F),                     \
                                     (lvoid_t*)(sb_ + 8192 + t16), 16, 0, 0);          \
    __builtin_amdgcn_global_load_lds((gvoid_t*)gB_,                                    \
                                     (lvoid_t*)(sb_ + 16384 + t16), 16, 0, 0);         \
  } while (0)

#define RDPH(S)                                                         \
  do {                                                                  \
    const char* Ab_ = (const char*)lds + (S) * 24576;                   \
    const char* Bb_ = Ab_ + 16384;                                      \
    _Pragma("unroll") for (int m = 0; m < 4; ++m)                       \
        a[m] = *(const half8*)(Ab_ + aoff + m * 1024);                  \
    _Pragma("unroll") for (int n = 0; n < 4; ++n)                       \
        b[n] = *(const half8*)(Bb_ + boff + n * 1024);                  \
  } while (0)

#define DOMFMA()                                                        \
  do {                                                                  \
    _Pragma("unroll") for (int m = 0; m < 4; ++m)                       \
        _Pragma("unroll") for (int n = 0; n < 4; ++n)                   \
            acc[m][n] = __builtin_amdgcn_mfma_f32_16x16x32_f16(         \
                a[m], b[n], acc[m][n], 0, 0, 0);                        \
  } while (0)

__global__ __launch_bounds__(512, 4) void gemm_k(const half_t* __restrict__ A,
                                                 const half_t* __restrict__ B,
                                                 const float* __restrict__ bias,
                                                 float* __restrict__ C) {
  __shared__ __align__(16) char lds[3 * 24576];  // 72 KiB -> 2 blocks/CU

  const int tid = threadIdx.x;
  const int lane = tid & 63;
  const int wv = tid >> 6;
  const int wr = wv & 3;       // 4 wave-rows (64 rows each)
  const int wc = wv >> 2;      // 2 wave-cols (64 cols each)
  const int t16 = tid * 16;    // linear stage dest byte

  // Raster: bn-chunks of 8 (last 6), bm-major, bn fastest within chunk.
  // nwg = 32 x 86 = 2752; per-XCD co-resident window (~64 blocks) = 8bm x 8bn.
  const int L = (int)blockIdx.x;
  const int c_ = (L >> 8) < 10 ? (L >> 8) : 10;  // chunk (256 blocks; last 192)
  const int r_ = L - (c_ << 8);
  const int w_ = (c_ == 10) ? 6 : 8;
  const int bm = (c_ == 10) ? (r_ / 6) : (r_ >> 3);
  const int bn = c_ * 8 + ((c_ == 10) ? (r_ % 6) : (r_ & 7));
  const int row0 = bm * BM;
  const int col0 = bn * BN;
  (void)w_;

  // staging source (pre-swizzled; involution c ^= (row&6)<<3).
  // dest row (within region round) = tid>>2, dest byte col = (tid&3)*16.
  const int c16 = (tid & 3) * 16;
  const int srow = tid >> 2;  // 0..127
  const int clog = c16 ^ ((srow & 6) << 3);
  const int kidx = clog >> 1;
  const half_t* pAsrc = A + (size_t)(row0 + srow) * IN_F + kidx;
  const half_t* pBsrc = B + (size_t)(col0 + srow) * IN_F + kidx;

  // fragment read offsets (swizzled); frag stride 16 rows * 64 B = 1024
  const int r16 = lane & 15;
  const int kg = lane >> 4;
  const int arow = wr * 64 + r16;
  const int brow = wc * 64 + r16;
  const int aoff = arow * 64 + ((kg * 16) ^ ((arow & 6) << 3));
  const int boff = brow * 64 + ((kg * 16) ^ ((brow & 6) << 3));

  f32x4 acc[4][4];
#pragma unroll
  for (int m = 0; m < 4; ++m)
#pragma unroll
    for (int n = 0; n < 4; ++n) acc[m][n] = (f32x4){0.f, 0.f, 0.f, 0.f};
  half8 a[4], b[4];

  // prologue: tiles 0,1 -> slots 0,1 (6 loads); vmcnt(3) = tile0 landed
  STAGE(0, 0);
  STAGE(1, 1);
  VMCNT(3);
  BAR();
  SB0();

  for (int t = 0; t < NKT - 2; ++t) {  // t = 0..125
    const int s = t % 3, s2 = (t + 2) % 3;
    RDPH(s);
    STAGE(t + 2, s2);
    SB0(); BAR();
    LGKM(0); SB0(); PRIO1();
    DOMFMA();
    PRIO0();
    VMCNT(3);  // retires tile t+1's group; leaves tile t+2's 3 loads in flight
    BAR(); SB0();
  }
  {  // t = 126: no stage; drain all (tile 127 lands)
    RDPH(0);  // 126 % 3 = 0
    SB0(); BAR();
    LGKM(0); SB0(); PRIO1();
    DOMFMA();
    PRIO0();
    VMCNT(0);
    BAR(); SB0();
  }
  {  // t = 127: slot 1, everything resident
    RDPH(1);
    LGKM(0); SB0();
    DOMFMA();
  }

  // epilogue: fp16 rounding + fp16 bias add (reference numerics), NT fp32 store.
  // C/D: col = lane&15, row = (lane>>4)*4 + r  [m89/m91]
  const int kg4 = kg * 4;
#pragma unroll
  for (int nf = 0; nf < 4; ++nf) {
    int col = col0 + wc * 64 + nf * 16 + r16;
    _Float16 bh = (_Float16)bias[col];
#pragma unroll
    for (int mf = 0; mf < 4; ++mf) {
      int rb = row0 + wr * 64 + mf * 16 + kg4;
#pragma unroll
      for (int r = 0; r < 4; ++r) {
        _Float16 v = (_Float16)acc[mf][nf][r] + bh;
        __builtin_nontemporal_store((float)v, &C[(size_t)(rb + r) * OUT_F + col]);
      }
    }
  }
}

// ---------------- emergency fallback (ws too small) ----------------
__global__ void naive_k(const float* __restrict__ x, const int* __restrict__ wq,
                        const float* __restrict__ scales, const float* __restrict__ bias,
                        float* __restrict__ out) {
  long idx = (long)blockIdx.x * blockDim.x + threadIdx.x;
  if (idx >= (long)M_TOTAL * OUT_F) return;
  int m = (int)(idx / OUT_F);
  int n = (int)(idx % OUT_F);
  float acc = 0.f;
  for (int g = 0; g < NGROUPS; ++g) {
    float s = scales[n * NGROUPS + g];
    for (int k = g * 128; k < (g + 1) * 128; ++k) {
      _Float16 xv = (_Float16)x[(size_t)m * IN_F + k];
      _Float16 wv = (_Float16)((float)wq[(size_t)n * IN_F + k] * s);
      acc += (float)xv * (float)wv;
    }
  }
  _Float16 r = (_Float16)acc + (_Float16)bias[n];
  out[idx] = (float)r;
}

extern "C" void kernel_launch(void* const* d_in, const int* in_sizes, int n_in,
                              void* d_out, int out_size, void* d_ws, size_t ws_size,
                              hipStream_t stream) {
  const float* x = (const float*)d_in[0];
  const int* wq = (const int*)d_in[1];
  const float* scales = (const float*)d_in[2];
  const float* bias = (const float*)d_in[3];
  float* out = (float*)d_out;

  const size_t xh_bytes = (size_t)M_TOTAL * IN_F * sizeof(half_t);
  const size_t wh_bytes = (size_t)OUT_F * IN_F * sizeof(half_t);

  if (ws_size >= xh_bytes + wh_bytes) {
    half_t* xh = (half_t*)d_ws;
    half_t* wh = (half_t*)((char*)d_ws + xh_bytes);
    convert_x_k<<<2048, 256, 0, stream>>>(x, xh);
    dequant_w_k<<<OUT_F, 512, 0, stream>>>(wq, scales, wh);
    gemm_k<<<(M_TOTAL / BM) * (OUT_F / BN), 512, 0, stream>>>(xh, wh, bias, out);
  } else {
    long total = (long)M_TOTAL * OUT_F;
    naive_k<<<(int)((total + 255) / 256), 256, 0, stream>>>(x, wq, scales, bias, out);
  }
}

// Round 11
// 831.645 us; speedup vs baseline: 1.2526x; 1.2526x over previous
//
#include <hip/hip_runtime.h>

#define IN_F 4096
#define OUT_F 11008
#define NGROUPS 32
#define M_TOTAL 8192
#define BM 256
#define BN 128
#define BK 32
#define NKT (IN_F / BK)  // 128 K-tiles

typedef _Float16 half_t;
typedef __attribute__((ext_vector_type(8))) _Float16 half8;
typedef __attribute__((ext_vector_type(4))) _Float16 half4v;
typedef __attribute__((ext_vector_type(4))) float f32x4;
typedef __attribute__((ext_vector_type(4))) int i32x4;

typedef __attribute__((address_space(1))) const void gvoid_t;
typedef __attribute__((address_space(3))) void lvoid_t;

// ---------------- prepass 1: x fp32 -> fp16 (RTNE) ----------------
__global__ void convert_x_k(const float* __restrict__ x, half_t* __restrict__ xh) {
  const int n4 = M_TOTAL * IN_F / 4;
  int stride = gridDim.x * blockDim.x;
  for (int i = blockIdx.x * blockDim.x + threadIdx.x; i < n4; i += stride) {
    f32x4 v = __builtin_nontemporal_load((const f32x4*)x + i);
    half4v h;
    h[0] = (_Float16)v[0]; h[1] = (_Float16)v[1];
    h[2] = (_Float16)v[2]; h[3] = (_Float16)v[3];
    ((half4v*)xh)[i] = h;
  }
}

// ---------------- prepass 2: W (int32-materialized int8) * group scale -> fp16 ----------
__global__ void dequant_w_k(const int* __restrict__ wq,
                            const float* __restrict__ scales,
                            half_t* __restrict__ wh) {
  int row = blockIdx.x;
  int t = threadIdx.x;  // 512 threads, 8 weights each
  size_t base = (size_t)row * IN_F + (size_t)t * 8;
  float s = scales[row * NGROUPS + (t >> 4)];
  i32x4 q0 = __builtin_nontemporal_load((const i32x4*)(wq + base));
  i32x4 q1 = __builtin_nontemporal_load((const i32x4*)(wq + base) + 1);
  half8 h;
#pragma unroll
  for (int j = 0; j < 4; ++j) h[j] = (_Float16)((float)q0[j] * s);
#pragma unroll
  for (int j = 0; j < 4; ++j) h[4 + j] = (_Float16)((float)q1[j] * s);
  *(half8*)(wh + base) = h;
}

// ---------------- 256x128 GEMM, 2 blocks/CU, 3-slot LDS rotation ----------------
// r10 structure + FIXED raster: XCD-bijective transform BEFORE the band map.
// L = (bid&7)*344 + bid>>3 (2752 = 8*344) -> per-XCD L contiguous; band map
// (chunks of 32bm x 8bn, bn fastest) -> 64-block co-resident window = 8bm x 8bn
// -> A-stripes x8- and B-stripes x8-shared in that XCD's L2.
// LDS slot (24 KiB): A [256][32k] (16 KiB) + B [128][32k] (8 KiB), 64 B rows,
// T2 swizzle c ^= (row&6)<<3 (pre-swizzled source + swizzled read).
// Phase t: rd slot t%3; stage tile t+2 -> slot (t+2)%3 (freed at t-1's end bar);
// BAR; lgkm0; 16 MFMA (16x16x32 f16); vmcnt(3) retires tile t+1's loads; BAR.

#define BAR() __builtin_amdgcn_s_barrier()
#define SB0() __builtin_amdgcn_sched_barrier(0)
#define PRIO1() __builtin_amdgcn_s_setprio(1)
#define PRIO0() __builtin_amdgcn_s_setprio(0)
#define VMCNT(N) asm volatile("s_waitcnt vmcnt(" #N ")" ::: "memory")
#define LGKM(N) asm volatile("s_waitcnt lgkmcnt(" #N ")" ::: "memory")

#define STAGE(KT, S)                                                                   \
  do {                                                                                 \
    char* sb_ = (char*)lds + (S) * 24576;                                              \
    const half_t* gA_ = pAsrc + (KT) * 32;                                             \
    const half_t* gB_ = pBsrc + (KT) * 32;                                             \
    __builtin_amdgcn_global_load_lds((gvoid_t*)gA_, (lvoid_t*)(sb_ + t16), 16, 0, 0);  \
    __builtin_amdgcn_global_load_lds((gvoid_t*)(gA_ + 128 * IN_F),                     \
                                     (lvoid_t*)(sb_ + 8192 + t16), 16, 0, 0);          \
    __builtin_amdgcn_global_load_lds((gvoid_t*)gB_,                                    \
                                     (lvoid_t*)(sb_ + 16384 + t16), 16, 0, 0);         \
  } while (0)

#define RDPH(S)                                                         \
  do {                                                                  \
    const char* Ab_ = (const char*)lds + (S) * 24576;                   \
    const char* Bb_ = Ab_ + 16384;                                      \
    _Pragma("unroll") for (int m = 0; m < 4; ++m)                       \
        a[m] = *(const half8*)(Ab_ + aoff + m * 1024);                  \
    _Pragma("unroll") for (int n = 0; n < 4; ++n)                       \
        b[n] = *(const half8*)(Bb_ + boff + n * 1024);                  \
  } while (0)

#define DOMFMA()                                                        \
  do {                                                                  \
    _Pragma("unroll") for (int m = 0; m < 4; ++m)                       \
        _Pragma("unroll") for (int n = 0; n < 4; ++n)                   \
            acc[m][n] = __builtin_amdgcn_mfma_f32_16x16x32_f16(         \
                a[m], b[n], acc[m][n], 0, 0, 0);                        \
  } while (0)

__global__ __launch_bounds__(512, 4) void gemm_k(const half_t* __restrict__ A,
                                                 const half_t* __restrict__ B,
                                                 const float* __restrict__ bias,
                                                 float* __restrict__ C) {
  __shared__ __align__(16) char lds[3 * 24576];  // 72 KiB -> 2 blocks/CU

  const int tid = threadIdx.x;
  const int lane = tid & 63;
  const int wv = tid >> 6;
  const int wr = wv & 3;       // 4 wave-rows (64 rows each)
  const int wc = wv >> 2;      // 2 wave-cols (64 cols each)
  const int t16 = tid * 16;    // linear stage dest byte

  // XCD-bijective transform, THEN band raster (chunks of 32bm x 8bn, bn fastest).
  const int bid = (int)blockIdx.x;
  const int L = (bid & 7) * 344 + (bid >> 3);    // nwg = 2752 = 8*344, bijective
  const int c_ = (L >> 8) < 10 ? (L >> 8) : 10;  // 10 full chunks of 256, last 192
  const int r_ = L - (c_ << 8);
  const int bm = (c_ == 10) ? (r_ / 6) : (r_ >> 3);
  const int bn = c_ * 8 + ((c_ == 10) ? (r_ % 6) : (r_ & 7));
  const int row0 = bm * BM;
  const int col0 = bn * BN;

  // staging source (pre-swizzled; involution c ^= (row&6)<<3)
  const int c16 = (tid & 3) * 16;
  const int srow = tid >> 2;  // 0..127
  const int clog = c16 ^ ((srow & 6) << 3);
  const int kidx = clog >> 1;
  const half_t* pAsrc = A + (size_t)(row0 + srow) * IN_F + kidx;
  const half_t* pBsrc = B + (size_t)(col0 + srow) * IN_F + kidx;

  // fragment read offsets (swizzled); frag stride 16 rows * 64 B = 1024
  const int r16 = lane & 15;
  const int kg = lane >> 4;
  const int arow = wr * 64 + r16;
  const int brow = wc * 64 + r16;
  const int aoff = arow * 64 + ((kg * 16) ^ ((arow & 6) << 3));
  const int boff = brow * 64 + ((kg * 16) ^ ((brow & 6) << 3));

  f32x4 acc[4][4];
#pragma unroll
  for (int m = 0; m < 4; ++m)
#pragma unroll
    for (int n = 0; n < 4; ++n) acc[m][n] = (f32x4){0.f, 0.f, 0.f, 0.f};
  half8 a[4], b[4];

  // prologue: tiles 0,1 -> slots 0,1 (6 loads); vmcnt(3) = tile0 landed
  STAGE(0, 0);
  STAGE(1, 1);
  VMCNT(3);
  BAR();
  SB0();

  for (int t = 0; t < NKT - 2; ++t) {  // t = 0..125
    const int s = t % 3, s2 = (t + 2) % 3;
    RDPH(s);
    STAGE(t + 2, s2);
    SB0(); BAR();
    LGKM(0); SB0(); PRIO1();
    DOMFMA();
    PRIO0();
    VMCNT(3);  // retires tile t+1's group; leaves tile t+2's 3 loads in flight
    BAR(); SB0();
  }
  {  // t = 126: no stage; drain all (tile 127 lands)
    RDPH(0);  // 126 % 3 = 0
    SB0(); BAR();
    LGKM(0); SB0(); PRIO1();
    DOMFMA();
    PRIO0();
    VMCNT(0);
    BAR(); SB0();
  }
  {  // t = 127: slot 1, everything resident
    RDPH(1);
    LGKM(0); SB0();
    DOMFMA();
  }

  // epilogue: fp16 rounding + fp16 bias add (reference numerics), NT fp32 store.
  // C/D: col = lane&15, row = (lane>>4)*4 + r  [m89/m91]
  const int kg4 = kg * 4;
#pragma unroll
  for (int nf = 0; nf < 4; ++nf) {
    int col = col0 + wc * 64 + nf * 16 + r16;
    _Float16 bh = (_Float16)bias[col];
#pragma unroll
    for (int mf = 0; mf < 4; ++mf) {
      int rb = row0 + wr * 64 + mf * 16 + kg4;
#pragma unroll
      for (int r = 0; r < 4; ++r) {
        _Float16 v = (_Float16)acc[mf][nf][r] + bh;
        __builtin_nontemporal_store((float)v, &C[(size_t)(rb + r) * OUT_F + col]);
      }
    }
  }
}

// ---------------- emergency fallback (ws too small) ----------------
__global__ void naive_k(const float* __restrict__ x, const int* __restrict__ wq,
                        const float* __restrict__ scales, const float* __restrict__ bias,
                        float* __restrict__ out) {
  long idx = (long)blockIdx.x * blockDim.x + threadIdx.x;
  if (idx >= (long)M_TOTAL * OUT_F) return;
  int m = (int)(idx / OUT_F);
  int n = (int)(idx % OUT_F);
  float acc = 0.f;
  for (int g = 0; g < NGROUPS; ++g) {
    float s = scales[n * NGROUPS + g];
    for (int k = g * 128; k < (g + 1) * 128; ++k) {
      _Float16 xv = (_Float16)x[(size_t)m * IN_F + k];
      _Float16 wv = (_Float16)((float)wq[(size_t)n * IN_F + k] * s);
      acc += (float)xv * (float)wv;
    }
  }
  _Float16 r = (_Float16)acc + (_Float16)bias[n];
  out[idx] = (float)r;
}

extern "C" void kernel_launch(void* const* d_in, const int* in_sizes, int n_in,
                              void* d_out, int out_size, void* d_ws, size_t ws_size,
                              hipStream_t stream) {
  const float* x = (const float*)d_in[0];
  const int* wq = (const int*)d_in[1];
  const float* scales = (const float*)d_in[2];
  const float* bias = (const float*)d_in[3];
  float* out = (float*)d_out;

  const size_t xh_bytes = (size_t)M_TOTAL * IN_F * sizeof(half_t);
  const size_t wh_bytes = (size_t)OUT_F * IN_F * sizeof(half_t);

  if (ws_size >= xh_bytes + wh_bytes) {
    half_t* xh = (half_t*)d_ws;
    half_t* wh = (half_t*)((char*)d_ws + xh_bytes);
    convert_x_k<<<2048, 256, 0, stream>>>(x, xh);
    dequant_w_k<<<OUT_F, 512, 0, stream>>>(wq, scales, wh);
    gemm_k<<<(M_TOTAL / BM) * (OUT_F / BN), 512, 0, stream>>>(xh, wh, bias, out);
  } else {
    long total = (long)M_TOTAL * OUT_F;
    naive_k<<<(int)((total + 255) / 256), 256, 0, stream>>>(x, wq, scales, bias, out);
  }
}

// Round 12
// 754.879 us; speedup vs baseline: 1.3800x; 1.1017x over previous
//
#include <hip/hip_runtime.h>

#define IN_F 4096
#define OUT_F 11008
#define NGROUPS 32
#define M_TOTAL 8192
#define BM 256
#define BN 256
#define BK 64
#define NKT (IN_F / BK)  // 64 K-tiles; 32 iters x (2 K-tiles / 4 merged phases)

typedef _Float16 half_t;
typedef __attribute__((ext_vector_type(8))) _Float16 half8;
typedef __attribute__((ext_vector_type(4))) _Float16 half4v;
typedef __attribute__((ext_vector_type(4))) float f32x4;
typedef __attribute__((ext_vector_type(4))) int i32x4;

typedef __attribute__((address_space(1))) const void gvoid_t;
typedef __attribute__((address_space(3))) void lvoid_t;

// ---------------- prepass 1: x fp32 -> fp16 (RTNE) ----------------
__global__ void convert_x_k(const float* __restrict__ x, half_t* __restrict__ xh) {
  const int n4 = M_TOTAL * IN_F / 4;
  int stride = gridDim.x * blockDim.x;
  for (int i = blockIdx.x * blockDim.x + threadIdx.x; i < n4; i += stride) {
    f32x4 v = __builtin_nontemporal_load((const f32x4*)x + i);
    half4v h;
    h[0] = (_Float16)v[0]; h[1] = (_Float16)v[1];
    h[2] = (_Float16)v[2]; h[3] = (_Float16)v[3];
    ((half4v*)xh)[i] = h;
  }
}

// ---------------- prepass 2: W (int32-materialized int8) * group scale -> fp16 ----------
__global__ void dequant_w_k(const int* __restrict__ wq,
                            const float* __restrict__ scales,
                            half_t* __restrict__ wh) {
  int row = blockIdx.x;
  int t = threadIdx.x;  // 512 threads, 8 weights each
  size_t base = (size_t)row * IN_F + (size_t)t * 8;
  float s = scales[row * NGROUPS + (t >> 4)];
  i32x4 q0 = __builtin_nontemporal_load((const i32x4*)(wq + base));
  i32x4 q1 = __builtin_nontemporal_load((const i32x4*)(wq + base) + 1);
  half8 h;
#pragma unroll
  for (int j = 0; j < 4; ++j) h[j] = (_Float16)((float)q0[j] * s);
#pragma unroll
  for (int j = 0; j < 4; ++j) h[4 + j] = (_Float16)((float)q1[j] * s);
  *(half8*)(wh + base) = h;
}

// ---------------- 256x256 GEMM, merged 4-phase, SINGLE barrier per phase ----------------
// r8 structure with the mid-phase barrier DELETED (it was lockstep-only; proof):
//  - stage safety: stage at phase p targets a region whose readers drained at their own
//    lgkmcnt(0) before their MFMA in phase p-1, hence before p-1's END barrier.
//  - tile visibility: each wave passes its own counted vmcnt(8) BEFORE the end barrier,
//    so at barrier release the 2-unit group read next phase is retired chip-wide.
// => one barrier per phase; waves free-run through read+stage+lgkm+MFMA, so wave W's
// MFMA overlaps wave V's LDS drain (the intra-block skew the mid-bar suppressed).
// LDS [slot][op][kh][256x32] fp16, 64 B rows, swizzle c ^= (row&6)<<3 (both sides).
// Stage map (iter u, t1=2u+1, n0=2u+2, n1=2u+3), 2 units/phase, vmcnt(8)/phase:
//   MP1(s0,kh0): {Ak1,Bk1}(t1)->s1   MP2(s0,kh1): {Ak0,Bk0}(n0)->s0
//   MP3(s1,kh0): {Ak1,Bk1}(n0)->s0   MP4(s1,kh1): {Ak0,Bk0}(n1)->s1

__device__ __forceinline__ void rd4(half8 (&d)[4], const char* base) {
#pragma unroll
  for (int i = 0; i < 4; ++i) d[i] = *(const half8*)(base + i * 1024);
}

__device__ __forceinline__ void mfma16(f32x4 (&acc)[8][4], const half8 (&a)[4],
                                       const half8 (&b)[4], int mh) {
#pragma unroll
  for (int i = 0; i < 4; ++i)
#pragma unroll
    for (int j = 0; j < 4; ++j)
      acc[mh * 4 + i][j] =
          __builtin_amdgcn_mfma_f32_16x16x32_f16(a[i], b[j], acc[mh * 4 + i][j], 0, 0, 0);
}

#define BAR() __builtin_amdgcn_s_barrier()
#define SB0() __builtin_amdgcn_sched_barrier(0)
#define PRIO1() __builtin_amdgcn_s_setprio(1)
#define PRIO0() __builtin_amdgcn_s_setprio(0)
#define VMCNT(N) asm volatile("s_waitcnt vmcnt(" #N ")" ::: "memory")
#define LGKM(N) asm volatile("s_waitcnt lgkmcnt(" #N ")" ::: "memory")

#define STAGE(OP, KH, KT, S)                                                          \
  do {                                                                                \
    const half_t* g_ = ((OP) ? pBsrc : pAsrc) + (KT) * 64 + (KH) * 32;                \
    char* d_ = (char*)&lds[S][OP][KH][0] + wvoff;                                     \
    __builtin_amdgcn_global_load_lds((gvoid_t*)g_, (lvoid_t*)d_, 16, 0, 0);           \
    __builtin_amdgcn_global_load_lds((gvoid_t*)(g_ + 128 * IN_F),                     \
                                     (lvoid_t*)(d_ + 8192), 16, 0, 0);                \
  } while (0)

// Merged phase, ONE barrier. FENCE: 8 = vmcnt(8), -1 = none
#define MPH(SL, KH, S1OP, S1KT, S1SL, S1KH, S2OP, S2KT, S2SL, S2KH, FENCE)   \
  do {                                                                       \
    rd4(a0, (const char*)&lds[SL][0][KH][0] + aoff);                         \
    rd4(a1, (const char*)&lds[SL][0][KH][0] + aoff + 4096);                  \
    rd4(b, (const char*)&lds[SL][1][KH][0] + boff);                          \
    STAGE(S1OP, S1KH, S1KT, S1SL);                                           \
    STAGE(S2OP, S2KH, S2KT, S2SL);                                           \
    LGKM(0); SB0(); PRIO1();                                                 \
    mfma16(acc, a0, b, 0);                                                   \
    mfma16(acc, a1, b, 1);                                                   \
    PRIO0();                                                                 \
    if ((FENCE) == 8) VMCNT(8);                                              \
    BAR(); SB0();                                                            \
  } while (0)

// Merged phase, no stages (peeled tail). FENCE: 8/4/0/-1
#define MPHN(SL, KH, FENCE)                                                  \
  do {                                                                       \
    rd4(a0, (const char*)&lds[SL][0][KH][0] + aoff);                         \
    rd4(a1, (const char*)&lds[SL][0][KH][0] + aoff + 4096);                  \
    rd4(b, (const char*)&lds[SL][1][KH][0] + boff);                          \
    LGKM(0); SB0(); PRIO1();                                                 \
    mfma16(acc, a0, b, 0);                                                   \
    mfma16(acc, a1, b, 1);                                                   \
    PRIO0();                                                                 \
    if ((FENCE) == 4) VMCNT(4);                                              \
    if ((FENCE) == 0) VMCNT(0);                                              \
    BAR(); SB0();                                                            \
  } while (0)

__global__ __launch_bounds__(512, 1) void gemm_k(const half_t* __restrict__ A,
                                                 const half_t* __restrict__ B,
                                                 const float* __restrict__ bias,
                                                 float* __restrict__ C) {
  __shared__ __align__(16) half_t lds[2][2][2][8192];  // 128 KiB

  const int tid = threadIdx.x;
  const int lane = tid & 63;
  const int wv = tid >> 6;
  const int wm = wv >> 2;      // 2 wave-rows (128 rows)
  const int wn = wv & 3;       // 4 wave-cols (64 cols)
  const int wvoff = wv << 10;

  // Band-rasterized, XCD-aware map (nwg = 1376 = 8*172, bijective):
  // bands of 32 bm x 4 bn, bn fastest -> co-resident window shares panels in L2.
  const int nwg = gridDim.x;
  const int perx = nwg >> 3;  // 172
  const int L = ((int)blockIdx.x & 7) * perx + ((int)blockIdx.x >> 3);
  const int band = L >> 7;
  const int rr_ = L & 127;
  const int bn0 = band << 2;
  const int cols = (43 - bn0) < 4 ? (43 - bn0) : 4;
  const int bm = rr_ / cols;
  const int bn = bn0 + rr_ % cols;
  const int row0 = bm * BM;
  const int col0 = bn * BN;

  // staging source (pre-swizzled; involution c ^= (row&6)<<3)
  const int c16 = (tid & 3) * 16;
  const int srow = tid >> 2;
  const int clog = c16 ^ ((srow & 6) << 3);
  const int kidx = clog >> 1;
  const half_t* pAsrc = A + (size_t)(row0 + srow) * IN_F + kidx;
  const half_t* pBsrc = B + (size_t)(col0 + srow) * IN_F + kidx;

  // fragment read offsets (swizzled); frag stride 16 rows * 64 B = 1024
  const int r16 = lane & 15;
  const int kg = lane >> 4;
  const int arow = wm * 128 + r16;
  const int brow = wn * 64 + r16;
  const int aoff = arow * 64 + ((kg * 16) ^ ((arow & 6) << 3));
  const int boff = brow * 64 + ((kg * 16) ^ ((brow & 6) << 3));

  f32x4 acc[8][4];
#pragma unroll
  for (int m = 0; m < 8; ++m)
#pragma unroll
    for (int n = 0; n < 4; ++n) acc[m][n] = (f32x4){0.f, 0.f, 0.f, 0.f};

  // prologue: tile0 all 4 units + tile1 {Ak0,Bk0}. vmcnt(4): tile0 landed.
  STAGE(0, 0, 0, 0);
  STAGE(1, 0, 0, 0);
  STAGE(0, 1, 0, 0);
  STAGE(1, 1, 0, 0);
  STAGE(0, 0, 1, 1);
  STAGE(1, 0, 1, 1);
  VMCNT(4);
  BAR();
  SB0();

  half8 a0[4], a1[4], b[4];
  for (int u = 0; u < 31; ++u) {
    const int t1 = 2 * u + 1, n0 = 2 * u + 2, n1 = 2 * u + 3;
    MPH(0, 0, 0, t1, 1, 1, 1, t1, 1, 1, 8);  // MP1: s0kh0; stage {Ak1,Bk1}(t1)->s1
    MPH(0, 1, 0, n0, 0, 0, 1, n0, 0, 0, 8);  // MP2: s0kh1; stage {Ak0,Bk0}(n0)->s0
    MPH(1, 0, 0, n0, 0, 1, 1, n0, 0, 1, 8);  // MP3: s1kh0; stage {Ak1,Bk1}(n0)->s0
    MPH(1, 1, 0, n1, 1, 0, 1, n1, 1, 0, 8);  // MP4: s1kh1; stage {Ak0,Bk0}(n1)->s1
  }
  {  // peeled iter 31 (t0=62, t1=63): MP1 stages {Ak1,Bk1}(63); drain 8/4/0
    MPH(0, 0, 0, 63, 1, 1, 1, 63, 1, 1, 8);
    MPHN(0, 1, 4);
    MPHN(1, 0, 0);
    MPHN(1, 1, -1);
  }

  // epilogue: fp16 rounding + fp16 bias add (reference numerics), NT fp32 store
  const int kg4 = kg * 4;
#pragma unroll
  for (int nf = 0; nf < 4; ++nf) {
    int col = col0 + wn * 64 + nf * 16 + r16;
    _Float16 bh = (_Float16)bias[col];
#pragma unroll
    for (int mf = 0; mf < 8; ++mf) {
      int rb = row0 + wm * 128 + mf * 16 + kg4;
#pragma unroll
      for (int r = 0; r < 4; ++r) {
        _Float16 v = (_Float16)acc[mf][nf][r] + bh;
        __builtin_nontemporal_store((float)v, &C[(size_t)(rb + r) * OUT_F + col]);
      }
    }
  }
}

// ---------------- emergency fallback (ws too small) ----------------
__global__ void naive_k(const float* __restrict__ x, const int* __restrict__ wq,
                        const float* __restrict__ scales, const float* __restrict__ bias,
                        float* __restrict__ out) {
  long idx = (long)blockIdx.x * blockDim.x + threadIdx.x;
  if (idx >= (long)M_TOTAL * OUT_F) return;
  int m = (int)(idx / OUT_F);
  int n = (int)(idx % OUT_F);
  float acc = 0.f;
  for (int g = 0; g < NGROUPS; ++g) {
    float s = scales[n * NGROUPS + g];
    for (int k = g * 128; k < (g + 1) * 128; ++k) {
      _Float16 xv = (_Float16)x[(size_t)m * IN_F + k];
      _Float16 wv = (_Float16)((float)wq[(size_t)n * IN_F + k] * s);
      acc += (float)xv * (float)wv;
    }
  }
  _Float16 r = (_Float16)acc + (_Float16)bias[n];
  out[idx] = (float)r;
}

extern "C" void kernel_launch(void* const* d_in, const int* in_sizes, int n_in,
                              void* d_out, int out_size, void* d_ws, size_t ws_size,
                              hipStream_t stream) {
  const float* x = (const float*)d_in[0];
  const int* wq = (const int*)d_in[1];
  const float* scales = (const float*)d_in[2];
  const float* bias = (const float*)d_in[3];
  float* out = (float*)d_out;

  const size_t xh_bytes = (size_t)M_TOTAL * IN_F * sizeof(half_t);
  const size_t wh_bytes = (size_t)OUT_F * IN_F * sizeof(half_t);

  if (ws_size >= xh_bytes + wh_bytes) {
    half_t* xh = (half_t*)d_ws;
    half_t* wh = (half_t*)((char*)d_ws + xh_bytes);
    convert_x_k<<<2048, 256, 0, stream>>>(x, xh);
    dequant_w_k<<<OUT_F, 512, 0, stream>>>(wq, scales, wh);
    gemm_k<<<(M_TOTAL / BM) * (OUT_F / BN), 512, 0, stream>>>(xh, wh, bias, out);
  } else {
    long total = (long)M_TOTAL * OUT_F;
    naive_k<<<(int)((total + 255) / 256), 256, 0, stream>>>(x, wq, scales, bias, out);
  }
}

// Round 13
// 727.533 us; speedup vs baseline: 1.4319x; 1.0376x over previous
//
#include <hip/hip_runtime.h>

#define IN_F 4096
#define OUT_F 11008
#define NGROUPS 32
#define M_TOTAL 8192
#define BM 256
#define BN 256
#define BK 64
#define NKT (IN_F / BK)  // 64 K-tiles; 32 iters x (2 K-tiles / 4 merged phases)

typedef _Float16 half_t;  // LDS element size only (2 B); payload is bf16 bits
typedef unsigned short ushort_t;
typedef __attribute__((ext_vector_type(8))) short short8;   // bf16x8 frag (4 VGPR)
typedef __attribute__((ext_vector_type(4))) float f32x4;
typedef __attribute__((ext_vector_type(4))) int i32x4;
typedef __attribute__((ext_vector_type(4))) unsigned short us4;

typedef __attribute__((address_space(1))) const void gvoid_t;
typedef __attribute__((address_space(3))) void lvoid_t;

__device__ __forceinline__ unsigned short f32_to_bf16_rne(float f) {
  unsigned int u = __builtin_bit_cast(unsigned int, f);
  u += 0x7FFFu + ((u >> 16) & 1u);
  return (unsigned short)(u >> 16);
}

// ---------------- prepass 1: x fp32 -> bf16 (RNE) ----------------
__global__ void convert_x_k(const float* __restrict__ x, ushort_t* __restrict__ xh) {
  const int n4 = M_TOTAL * IN_F / 4;
  int stride = gridDim.x * blockDim.x;
  for (int i = blockIdx.x * blockDim.x + threadIdx.x; i < n4; i += stride) {
    f32x4 v = __builtin_nontemporal_load((const f32x4*)x + i);
    us4 h;
    h[0] = f32_to_bf16_rne(v[0]);
    h[1] = f32_to_bf16_rne(v[1]);
    h[2] = f32_to_bf16_rne(v[2]);
    h[3] = f32_to_bf16_rne(v[3]);
    ((us4*)xh)[i] = h;
  }
}

// ---------------- prepass 2: W (int32-materialized int8) * group scale -> bf16 ----------
__global__ void dequant_w_k(const int* __restrict__ wq,
                            const float* __restrict__ scales,
                            ushort_t* __restrict__ wh) {
  int row = blockIdx.x;
  int t = threadIdx.x;  // 512 threads, 8 weights each
  size_t base = (size_t)row * IN_F + (size_t)t * 8;
  float s = scales[row * NGROUPS + (t >> 4)];
  i32x4 q0 = __builtin_nontemporal_load((const i32x4*)(wq + base));
  i32x4 q1 = __builtin_nontemporal_load((const i32x4*)(wq + base) + 1);
  us4 h0, h1;
#pragma unroll
  for (int j = 0; j < 4; ++j) h0[j] = f32_to_bf16_rne((float)q0[j] * s);
#pragma unroll
  for (int j = 0; j < 4; ++j) h1[j] = f32_to_bf16_rne((float)q1[j] * s);
  *(us4*)(wh + base) = h0;
  *(us4*)(wh + base + 4) = h1;
}

// ---------------- 256x256 GEMM, merged 4-phase, single barrier/phase, bf16 ----------------
// r12 structure verbatim; dtype switched f16 -> bf16 (pipe 1955 -> 2075 TF, m64/m06).
// LDS [slot][op][kh][256x32] bf16, 64 B rows, swizzle c ^= (row&6)<<3 (both sides).
// Stage map (iter u, t1=2u+1, n0=2u+2, n1=2u+3), 2 units/phase, vmcnt(8)/phase:
//   MP1(s0,kh0): {Ak1,Bk1}(t1)->s1   MP2(s0,kh1): {Ak0,Bk0}(n0)->s0
//   MP3(s1,kh0): {Ak1,Bk1}(n0)->s0   MP4(s1,kh1): {Ak0,Bk0}(n1)->s1
// Single barrier/phase proof: stage at p targets a region whose readers drained at
// their own lgkmcnt(0) before their MFMA in p-1, hence before p-1's end barrier;
// each wave passes its counted vmcnt(8) BEFORE the end barrier, so at release the
// 2-unit group read next phase is retired chip-wide.

__device__ __forceinline__ void rd4(short8 (&d)[4], const char* base) {
#pragma unroll
  for (int i = 0; i < 4; ++i) d[i] = *(const short8*)(base + i * 1024);
}

__device__ __forceinline__ void mfma16(f32x4 (&acc)[8][4], const short8 (&a)[4],
                                       const short8 (&b)[4], int mh) {
#pragma unroll
  for (int i = 0; i < 4; ++i)
#pragma unroll
    for (int j = 0; j < 4; ++j)
      acc[mh * 4 + i][j] =
          __builtin_amdgcn_mfma_f32_16x16x32_bf16(a[i], b[j], acc[mh * 4 + i][j], 0, 0, 0);
}

#define BAR() __builtin_amdgcn_s_barrier()
#define SB0() __builtin_amdgcn_sched_barrier(0)
#define PRIO1() __builtin_amdgcn_s_setprio(1)
#define PRIO0() __builtin_amdgcn_s_setprio(0)
#define VMCNT(N) asm volatile("s_waitcnt vmcnt(" #N ")" ::: "memory")
#define LGKM(N) asm volatile("s_waitcnt lgkmcnt(" #N ")" ::: "memory")

#define STAGE(OP, KH, KT, S)                                                          \
  do {                                                                                \
    const half_t* g_ = ((OP) ? pBsrc : pAsrc) + (KT) * 64 + (KH) * 32;                \
    char* d_ = (char*)&lds[S][OP][KH][0] + wvoff;                                     \
    __builtin_amdgcn_global_load_lds((gvoid_t*)g_, (lvoid_t*)d_, 16, 0, 0);           \
    __builtin_amdgcn_global_load_lds((gvoid_t*)(g_ + 128 * IN_F),                     \
                                     (lvoid_t*)(d_ + 8192), 16, 0, 0);                \
  } while (0)

// Merged phase, ONE barrier. FENCE: 8 = vmcnt(8), -1 = none
#define MPH(SL, KH, S1OP, S1KT, S1SL, S1KH, S2OP, S2KT, S2SL, S2KH, FENCE)   \
  do {                                                                       \
    rd4(a0, (const char*)&lds[SL][0][KH][0] + aoff);                         \
    rd4(a1, (const char*)&lds[SL][0][KH][0] + aoff + 4096);                  \
    rd4(b, (const char*)&lds[SL][1][KH][0] + boff);                          \
    STAGE(S1OP, S1KH, S1KT, S1SL);                                           \
    STAGE(S2OP, S2KH, S2KT, S2SL);                                           \
    LGKM(0); SB0(); PRIO1();                                                 \
    mfma16(acc, a0, b, 0);                                                   \
    mfma16(acc, a1, b, 1);                                                   \
    PRIO0();                                                                 \
    if ((FENCE) == 8) VMCNT(8);                                              \
    BAR(); SB0();                                                            \
  } while (0)

// Merged phase, no stages (peeled tail). FENCE: 8/4/0/-1
#define MPHN(SL, KH, FENCE)                                                  \
  do {                                                                       \
    rd4(a0, (const char*)&lds[SL][0][KH][0] + aoff);                         \
    rd4(a1, (const char*)&lds[SL][0][KH][0] + aoff + 4096);                  \
    rd4(b, (const char*)&lds[SL][1][KH][0] + boff);                          \
    LGKM(0); SB0(); PRIO1();                                                 \
    mfma16(acc, a0, b, 0);                                                   \
    mfma16(acc, a1, b, 1);                                                   \
    PRIO0();                                                                 \
    if ((FENCE) == 4) VMCNT(4);                                              \
    if ((FENCE) == 0) VMCNT(0);                                              \
    BAR(); SB0();                                                            \
  } while (0)

__global__ __launch_bounds__(512, 1) void gemm_k(const half_t* __restrict__ A,
                                                 const half_t* __restrict__ B,
                                                 const float* __restrict__ bias,
                                                 float* __restrict__ C) {
  __shared__ __align__(16) half_t lds[2][2][2][8192];  // 128 KiB

  const int tid = threadIdx.x;
  const int lane = tid & 63;
  const int wv = tid >> 6;
  const int wm = wv >> 2;      // 2 wave-rows (128 rows)
  const int wn = wv & 3;       // 4 wave-cols (64 cols)
  const int wvoff = wv << 10;

  // Band-rasterized, XCD-aware map (nwg = 1376 = 8*172, bijective):
  const int nwg = gridDim.x;
  const int perx = nwg >> 3;  // 172
  const int L = ((int)blockIdx.x & 7) * perx + ((int)blockIdx.x >> 3);
  const int band = L >> 7;
  const int rr_ = L & 127;
  const int bn0 = band << 2;
  const int cols = (43 - bn0) < 4 ? (43 - bn0) : 4;
  const int bm = rr_ / cols;
  const int bn = bn0 + rr_ % cols;
  const int row0 = bm * BM;
  const int col0 = bn * BN;

  // staging source (pre-swizzled; involution c ^= (row&6)<<3)
  const int c16 = (tid & 3) * 16;
  const int srow = tid >> 2;
  const int clog = c16 ^ ((srow & 6) << 3);
  const int kidx = clog >> 1;
  const half_t* pAsrc = A + (size_t)(row0 + srow) * IN_F + kidx;
  const half_t* pBsrc = B + (size_t)(col0 + srow) * IN_F + kidx;

  // fragment read offsets (swizzled); frag stride 16 rows * 64 B = 1024
  const int r16 = lane & 15;
  const int kg = lane >> 4;
  const int arow = wm * 128 + r16;
  const int brow = wn * 64 + r16;
  const int aoff = arow * 64 + ((kg * 16) ^ ((arow & 6) << 3));
  const int boff = brow * 64 + ((kg * 16) ^ ((brow & 6) << 3));

  f32x4 acc[8][4];
#pragma unroll
  for (int m = 0; m < 8; ++m)
#pragma unroll
    for (int n = 0; n < 4; ++n) acc[m][n] = (f32x4){0.f, 0.f, 0.f, 0.f};

  // prologue: tile0 all 4 units + tile1 {Ak0,Bk0}. vmcnt(4): tile0 landed.
  STAGE(0, 0, 0, 0);
  STAGE(1, 0, 0, 0);
  STAGE(0, 1, 0, 0);
  STAGE(1, 1, 0, 0);
  STAGE(0, 0, 1, 1);
  STAGE(1, 0, 1, 1);
  VMCNT(4);
  BAR();
  SB0();

  short8 a0[4], a1[4], b[4];
  for (int u = 0; u < 31; ++u) {
    const int t1 = 2 * u + 1, n0 = 2 * u + 2, n1 = 2 * u + 3;
    MPH(0, 0, 0, t1, 1, 1, 1, t1, 1, 1, 8);  // MP1: s0kh0; stage {Ak1,Bk1}(t1)->s1
    MPH(0, 1, 0, n0, 0, 0, 1, n0, 0, 0, 8);  // MP2: s0kh1; stage {Ak0,Bk0}(n0)->s0
    MPH(1, 0, 0, n0, 0, 1, 1, n0, 0, 1, 8);  // MP3: s1kh0; stage {Ak1,Bk1}(n0)->s0
    MPH(1, 1, 0, n1, 1, 0, 1, n1, 1, 0, 8);  // MP4: s1kh1; stage {Ak0,Bk0}(n1)->s1
  }
  {  // peeled iter 31 (t0=62, t1=63): MP1 stages {Ak1,Bk1}(63); drain 8/4/0
    MPH(0, 0, 0, 63, 1, 1, 1, 63, 1, 1, 8);
    MPHN(0, 1, 4);
    MPHN(1, 0, 0);
    MPHN(1, 1, -1);
  }

  // epilogue: fp16 rounding + fp16 bias add (reference numerics), NT fp32 store
  const int kg4 = kg * 4;
#pragma unroll
  for (int nf = 0; nf < 4; ++nf) {
    int col = col0 + wn * 64 + nf * 16 + r16;
    _Float16 bh = (_Float16)bias[col];
#pragma unroll
    for (int mf = 0; mf < 8; ++mf) {
      int rb = row0 + wm * 128 + mf * 16 + kg4;
#pragma unroll
      for (int r = 0; r < 4; ++r) {
        _Float16 v = (_Float16)acc[mf][nf][r] + bh;
        __builtin_nontemporal_store((float)v, &C[(size_t)(rb + r) * OUT_F + col]);
      }
    }
  }
}

// ---------------- emergency fallback (ws too small) ----------------
__global__ void naive_k(const float* __restrict__ x, const int* __restrict__ wq,
                        const float* __restrict__ scales, const float* __restrict__ bias,
                        float* __restrict__ out) {
  long idx = (long)blockIdx.x * blockDim.x + threadIdx.x;
  if (idx >= (long)M_TOTAL * OUT_F) return;
  int m = (int)(idx / OUT_F);
  int n = (int)(idx % OUT_F);
  float acc = 0.f;
  for (int g = 0; g < NGROUPS; ++g) {
    float s = scales[n * NGROUPS + g];
    for (int k = g * 128; k < (g + 1) * 128; ++k) {
      _Float16 xv = (_Float16)x[(size_t)m * IN_F + k];
      _Float16 wv = (_Float16)((float)wq[(size_t)n * IN_F + k] * s);
      acc += (float)xv * (float)wv;
    }
  }
  _Float16 r = (_Float16)acc + (_Float16)bias[n];
  out[idx] = (float)r;
}

extern "C" void kernel_launch(void* const* d_in, const int* in_sizes, int n_in,
                              void* d_out, int out_size, void* d_ws, size_t ws_size,
                              hipStream_t stream) {
  const float* x = (const float*)d_in[0];
  const int* wq = (const int*)d_in[1];
  const float* scales = (const float*)d_in[2];
  const float* bias = (const float*)d_in[3];
  float* out = (float*)d_out;

  const size_t xh_bytes = (size_t)M_TOTAL * IN_F * 2;
  const size_t wh_bytes = (size_t)OUT_F * IN_F * 2;

  if (ws_size >= xh_bytes + wh_bytes) {
    ushort_t* xh = (ushort_t*)d_ws;
    ushort_t* wh = (ushort_t*)((char*)d_ws + xh_bytes);
    convert_x_k<<<2048, 256, 0, stream>>>(x, xh);
    dequant_w_k<<<OUT_F, 512, 0, stream>>>(wq, scales, wh);
    gemm_k<<<(M_TOTAL / BM) * (OUT_F / BN), 512, 0, stream>>>(
        (const half_t*)xh, (const half_t*)wh, bias, out);
  } else {
    long total = (long)M_TOTAL * OUT_F;
    naive_k<<<(int)((total + 255) / 256), 256, 0, stream>>>(x, wq, scales, bias, out);
  }
}

// Round 14
// 716.314 us; speedup vs baseline: 1.4543x; 1.0157x over previous
//
#include <hip/hip_runtime.h>

#define IN_F 4096
#define OUT_F 11008
#define NGROUPS 32
#define M_TOTAL 8192
#define BM 256
#define BN 256
#define BK 64
#define NKT (IN_F / BK)  // 64 K-tiles; 32 iters x (2 K-tiles / 4 merged phases)

typedef _Float16 half_t;  // LDS element size only (2 B); payload is bf16 bits
typedef unsigned short ushort_t;
typedef __attribute__((ext_vector_type(8))) short short8;   // bf16x8 frag (4 VGPR)
typedef __attribute__((ext_vector_type(4))) float f32x4;
typedef __attribute__((ext_vector_type(4))) int i32x4;
typedef __attribute__((ext_vector_type(4))) unsigned short us4;

typedef __attribute__((address_space(1))) const void gvoid_t;
typedef __attribute__((address_space(3))) void lvoid_t;

__device__ __forceinline__ unsigned short f32_to_bf16_rne(float f) {
  unsigned int u = __builtin_bit_cast(unsigned int, f);
  u += 0x7FFFu + ((u >> 16) & 1u);
  return (unsigned short)(u >> 16);
}

// ---------------- prepass 1: x fp32 -> bf16 (RNE) ----------------
__global__ void convert_x_k(const float* __restrict__ x, ushort_t* __restrict__ xh) {
  const int n4 = M_TOTAL * IN_F / 4;
  int stride = gridDim.x * blockDim.x;
  for (int i = blockIdx.x * blockDim.x + threadIdx.x; i < n4; i += stride) {
    f32x4 v = __builtin_nontemporal_load((const f32x4*)x + i);
    us4 h;
    h[0] = f32_to_bf16_rne(v[0]);
    h[1] = f32_to_bf16_rne(v[1]);
    h[2] = f32_to_bf16_rne(v[2]);
    h[3] = f32_to_bf16_rne(v[3]);
    ((us4*)xh)[i] = h;
  }
}

// ---------------- prepass 2: W (int32-materialized int8) * group scale -> bf16 ----------
__global__ void dequant_w_k(const int* __restrict__ wq,
                            const float* __restrict__ scales,
                            ushort_t* __restrict__ wh) {
  int row = blockIdx.x;
  int t = threadIdx.x;  // 512 threads, 8 weights each
  size_t base = (size_t)row * IN_F + (size_t)t * 8;
  float s = scales[row * NGROUPS + (t >> 4)];
  i32x4 q0 = __builtin_nontemporal_load((const i32x4*)(wq + base));
  i32x4 q1 = __builtin_nontemporal_load((const i32x4*)(wq + base) + 1);
  us4 h0, h1;
#pragma unroll
  for (int j = 0; j < 4; ++j) h0[j] = f32_to_bf16_rne((float)q0[j] * s);
#pragma unroll
  for (int j = 0; j < 4; ++j) h1[j] = f32_to_bf16_rne((float)q1[j] * s);
  *(us4*)(wh + base) = h0;
  *(us4*)(wh + base + 4) = h1;
}

// ---------- 256x256 GEMM, merged 4-phase, single barrier, SPLIT lgkm wait ----------
// r13 + one change: reads ordered a0,b,a1 (SB0-pinned; DS returns in-order per wave);
// lgkmcnt(4) -> a0+b done -> 16 MFMA (mh0); lgkmcnt(0) -> a1 -> 16 MFMA (mh1).
// Each wave starts MFMA after 8/12 reads: the tail of the 96-read/CU LDS queue
// overlaps the first MFMA burst instead of serializing before it.
// LDS [slot][op][kh][256x32] bf16, 64 B rows, swizzle c ^= (row&6)<<3 (both sides).
// Stage map (iter u, t1=2u+1, n0=2u+2, n1=2u+3), 2 units/phase, vmcnt(8)/phase:
//   MP1(s0,kh0): {Ak1,Bk1}(t1)->s1   MP2(s0,kh1): {Ak0,Bk0}(n0)->s0
//   MP3(s1,kh0): {Ak1,Bk1}(n0)->s0   MP4(s1,kh1): {Ak0,Bk0}(n1)->s1
// (ledger unchanged from r8/r12: stage targets freed at prior end-barrier; each wave
//  passes its counted vmcnt BEFORE the end barrier -> staged group visible at release.)

__device__ __forceinline__ void rd4(short8 (&d)[4], const char* base) {
#pragma unroll
  for (int i = 0; i < 4; ++i) d[i] = *(const short8*)(base + i * 1024);
}

__device__ __forceinline__ void mfma16(f32x4 (&acc)[8][4], const short8 (&a)[4],
                                       const short8 (&b)[4], int mh) {
#pragma unroll
  for (int i = 0; i < 4; ++i)
#pragma unroll
    for (int j = 0; j < 4; ++j)
      acc[mh * 4 + i][j] =
          __builtin_amdgcn_mfma_f32_16x16x32_bf16(a[i], b[j], acc[mh * 4 + i][j], 0, 0, 0);
}

#define BAR() __builtin_amdgcn_s_barrier()
#define SB0() __builtin_amdgcn_sched_barrier(0)
#define PRIO1() __builtin_amdgcn_s_setprio(1)
#define PRIO0() __builtin_amdgcn_s_setprio(0)
#define VMCNT(N) asm volatile("s_waitcnt vmcnt(" #N ")" ::: "memory")
#define LGKM(N) asm volatile("s_waitcnt lgkmcnt(" #N ")" ::: "memory")

#define STAGE(OP, KH, KT, S)                                                          \
  do {                                                                                \
    const half_t* g_ = ((OP) ? pBsrc : pAsrc) + (KT) * 64 + (KH) * 32;                \
    char* d_ = (char*)&lds[S][OP][KH][0] + wvoff;                                     \
    __builtin_amdgcn_global_load_lds((gvoid_t*)g_, (lvoid_t*)d_, 16, 0, 0);           \
    __builtin_amdgcn_global_load_lds((gvoid_t*)(g_ + 128 * IN_F),                     \
                                     (lvoid_t*)(d_ + 8192), 16, 0, 0);                \
  } while (0)

// Merged phase, ONE barrier, split lgkm. FENCE: 8 = vmcnt(8), -1 = none
#define MPH(SL, KH, S1OP, S1KT, S1SL, S1KH, S2OP, S2KT, S2SL, S2KH, FENCE)   \
  do {                                                                       \
    rd4(a0, (const char*)&lds[SL][0][KH][0] + aoff);                         \
    rd4(b, (const char*)&lds[SL][1][KH][0] + boff);                          \
    SB0();  /* pin: a0+b issue before a1 (in-order DS returns) */            \
    rd4(a1, (const char*)&lds[SL][0][KH][0] + aoff + 4096);                  \
    STAGE(S1OP, S1KH, S1KT, S1SL);                                           \
    STAGE(S2OP, S2KH, S2KT, S2SL);                                           \
    LGKM(4); SB0(); PRIO1();  /* a0 + b landed */                            \
    mfma16(acc, a0, b, 0);                                                   \
    LGKM(0); SB0();           /* a1 landed */                                \
    mfma16(acc, a1, b, 1);                                                   \
    PRIO0();                                                                 \
    if ((FENCE) == 8) VMCNT(8);                                              \
    BAR(); SB0();                                                            \
  } while (0)

// Merged phase, no stages (peeled tail). FENCE: 8/4/0/-1
#define MPHN(SL, KH, FENCE)                                                  \
  do {                                                                       \
    rd4(a0, (const char*)&lds[SL][0][KH][0] + aoff);                         \
    rd4(b, (const char*)&lds[SL][1][KH][0] + boff);                          \
    SB0();                                                                   \
    rd4(a1, (const char*)&lds[SL][0][KH][0] + aoff + 4096);                  \
    LGKM(4); SB0(); PRIO1();                                                 \
    mfma16(acc, a0, b, 0);                                                   \
    LGKM(0); SB0();                                                          \
    mfma16(acc, a1, b, 1);                                                   \
    PRIO0();                                                                 \
    if ((FENCE) == 4) VMCNT(4);                                              \
    if ((FENCE) == 0) VMCNT(0);                                              \
    BAR(); SB0();                                                            \
  } while (0)

__global__ __launch_bounds__(512, 1) void gemm_k(const half_t* __restrict__ A,
                                                 const half_t* __restrict__ B,
                                                 const float* __restrict__ bias,
                                                 float* __restrict__ C) {
  __shared__ __align__(16) half_t lds[2][2][2][8192];  // 128 KiB

  const int tid = threadIdx.x;
  const int lane = tid & 63;
  const int wv = tid >> 6;
  const int wm = wv >> 2;      // 2 wave-rows (128 rows)
  const int wn = wv & 3;       // 4 wave-cols (64 cols)
  const int wvoff = wv << 10;

  // Band-rasterized, XCD-aware map (nwg = 1376 = 8*172, bijective):
  const int nwg = gridDim.x;
  const int perx = nwg >> 3;  // 172
  const int L = ((int)blockIdx.x & 7) * perx + ((int)blockIdx.x >> 3);
  const int band = L >> 7;
  const int rr_ = L & 127;
  const int bn0 = band << 2;
  const int cols = (43 - bn0) < 4 ? (43 - bn0) : 4;
  const int bm = rr_ / cols;
  const int bn = bn0 + rr_ % cols;
  const int row0 = bm * BM;
  const int col0 = bn * BN;

  // staging source (pre-swizzled; involution c ^= (row&6)<<3)
  const int c16 = (tid & 3) * 16;
  const int srow = tid >> 2;
  const int clog = c16 ^ ((srow & 6) << 3);
  const int kidx = clog >> 1;
  const half_t* pAsrc = A + (size_t)(row0 + srow) * IN_F + kidx;
  const half_t* pBsrc = B + (size_t)(col0 + srow) * IN_F + kidx;

  // fragment read offsets (swizzled); frag stride 16 rows * 64 B = 1024
  const int r16 = lane & 15;
  const int kg = lane >> 4;
  const int arow = wm * 128 + r16;
  const int brow = wn * 64 + r16;
  const int aoff = arow * 64 + ((kg * 16) ^ ((arow & 6) << 3));
  const int boff = brow * 64 + ((kg * 16) ^ ((brow & 6) << 3));

  f32x4 acc[8][4];
#pragma unroll
  for (int m = 0; m < 8; ++m)
#pragma unroll
    for (int n = 0; n < 4; ++n) acc[m][n] = (f32x4){0.f, 0.f, 0.f, 0.f};

  // prologue: tile0 all 4 units + tile1 {Ak0,Bk0}. vmcnt(4): tile0 landed.
  STAGE(0, 0, 0, 0);
  STAGE(1, 0, 0, 0);
  STAGE(0, 1, 0, 0);
  STAGE(1, 1, 0, 0);
  STAGE(0, 0, 1, 1);
  STAGE(1, 0, 1, 1);
  VMCNT(4);
  BAR();
  SB0();

  short8 a0[4], a1[4], b[4];
  for (int u = 0; u < 31; ++u) {
    const int t1 = 2 * u + 1, n0 = 2 * u + 2, n1 = 2 * u + 3;
    MPH(0, 0, 0, t1, 1, 1, 1, t1, 1, 1, 8);  // MP1: s0kh0; stage {Ak1,Bk1}(t1)->s1
    MPH(0, 1, 0, n0, 0, 0, 1, n0, 0, 0, 8);  // MP2: s0kh1; stage {Ak0,Bk0}(n0)->s0
    MPH(1, 0, 0, n0, 0, 1, 1, n0, 0, 1, 8);  // MP3: s1kh0; stage {Ak1,Bk1}(n0)->s0
    MPH(1, 1, 0, n1, 1, 0, 1, n1, 1, 0, 8);  // MP4: s1kh1; stage {Ak0,Bk0}(n1)->s1
  }
  {  // peeled iter 31 (t0=62, t1=63): MP1 stages {Ak1,Bk1}(63); drain 8/4/0
    MPH(0, 0, 0, 63, 1, 1, 1, 63, 1, 1, 8);
    MPHN(0, 1, 4);
    MPHN(1, 0, 0);
    MPHN(1, 1, -1);
  }

  // epilogue: fp16 rounding + fp16 bias add (reference numerics), NT fp32 store
  const int kg4 = kg * 4;
#pragma unroll
  for (int nf = 0; nf < 4; ++nf) {
    int col = col0 + wn * 64 + nf * 16 + r16;
    _Float16 bh = (_Float16)bias[col];
#pragma unroll
    for (int mf = 0; mf < 8; ++mf) {
      int rb = row0 + wm * 128 + mf * 16 + kg4;
#pragma unroll
      for (int r = 0; r < 4; ++r) {
        _Float16 v = (_Float16)acc[mf][nf][r] + bh;
        __builtin_nontemporal_store((float)v, &C[(size_t)(rb + r) * OUT_F + col]);
      }
    }
  }
}

// ---------------- emergency fallback (ws too small) ----------------
__global__ void naive_k(const float* __restrict__ x, const int* __restrict__ wq,
                        const float* __restrict__ scales, const float* __restrict__ bias,
                        float* __restrict__ out) {
  long idx = (long)blockIdx.x * blockDim.x + threadIdx.x;
  if (idx >= (long)M_TOTAL * OUT_F) return;
  int m = (int)(idx / OUT_F);
  int n = (int)(idx % OUT_F);
  float acc = 0.f;
  for (int g = 0; g < NGROUPS; ++g) {
    float s = scales[n * NGROUPS + g];
    for (int k = g * 128; k < (g + 1) * 128; ++k) {
      _Float16 xv = (_Float16)x[(size_t)m * IN_F + k];
      _Float16 wv = (_Float16)((float)wq[(size_t)n * IN_F + k] * s);
      acc += (float)xv * (float)wv;
    }
  }
  _Float16 r = (_Float16)acc + (_Float16)bias[n];
  out[idx] = (float)r;
}

extern "C" void kernel_launch(void* const* d_in, const int* in_sizes, int n_in,
                              void* d_out, int out_size, void* d_ws, size_t ws_size,
                              hipStream_t stream) {
  const float* x = (const float*)d_in[0];
  const int* wq = (const int*)d_in[1];
  const float* scales = (const float*)d_in[2];
  const float* bias = (const float*)d_in[3];
  float* out = (float*)d_out;

  const size_t xh_bytes = (size_t)M_TOTAL * IN_F * 2;
  const size_t wh_bytes = (size_t)OUT_F * IN_F * 2;

  if (ws_size >= xh_bytes + wh_bytes) {
    ushort_t* xh = (ushort_t*)d_ws;
    ushort_t* wh = (ushort_t*)((char*)d_ws + xh_bytes);
    convert_x_k<<<2048, 256, 0, stream>>>(x, xh);
    dequant_w_k<<<OUT_F, 512, 0, stream>>>(wq, scales, wh);
    gemm_k<<<(M_TOTAL / BM) * (OUT_F / BN), 512, 0, stream>>>(
        (const half_t*)xh, (const half_t*)wh, bias, out);
  } else {
    long total = (long)M_TOTAL * OUT_F;
    naive_k<<<(int)((total + 255) / 256), 256, 0, stream>>>(x, wq, scales, bias, out);
  }
}